// Round 7
// baseline (236.506 us; speedup 1.0000x reference)
//
#include <hip/hip_runtime.h>
#include <hip/hip_bf16.h>
#include <string.h>

// DeformableConv2d: B=4, C=256, O=256, H=W=64, K=3, pad=1, stride=1
// Round 7: revert to round-5 source (bit-stable, 235us) with ONE change:
//   K2 build(): hoist all 32 independent x-loads into v[32] before pack/ds_write
//   (+ sched_barrier(0) so the scheduler can't sink loads back to uses).
//   Theory: K2's hidden ~100us = per-load vmcnt(0) serialization under a
//   register-starved allocator (32 loads x ~900cyc L3 x 9 intervals = 108us).
// K1, K3 byte-identical to round 5.
// Workspace: ws_off 1769472 B | ws_b 1179648 B | ws_a2 147456 B = 3096576 B.

typedef __attribute__((ext_vector_type(8))) short short8;
typedef __attribute__((ext_vector_type(8))) _Float16 half8;
typedef __attribute__((ext_vector_type(16))) float floatx16;

__device__ __forceinline__ unsigned bfbits(float f) {
    unsigned u;
    __builtin_memcpy(&u, &f, 4);
    return (u + 0x7fffu + ((u >> 16) & 1u)) >> 16;   // RNE f32->bf16
}
__device__ __forceinline__ unsigned pack_bf16(float lo, float hi) {
    return bfbits(lo) | (bfbits(hi) << 16);
}
__device__ __forceinline__ unsigned pack_f16(float lo, float hi) {
    _Float16 a = (_Float16)lo, b = (_Float16)hi;
    unsigned short ua, ub;
    __builtin_memcpy(&ua, &a, 2);
    __builtin_memcpy(&ub, &b, 2);
    return (unsigned)ua | ((unsigned)ub << 16);
}

// ---------------------------------------------------------------------------
// K1: weight pack (verbatim round 4/5).
// ---------------------------------------------------------------------------
__global__ __launch_bounds__(256) void weight_pack_kernel(
    const float* __restrict__ w, const float* __restrict__ off_w,
    const float* __restrict__ mask_w,
    unsigned short* __restrict__ ws_b, unsigned short* __restrict__ ws_a2)
{
    __shared__ float slab[32 * 289];
    const int bid = blockIdx.x;
    const int tid = threadIdx.x;

    if (bid < 64) {
        const int nt = bid >> 3, cb = bid & 7;
        const float* wbase = w + (size_t)nt * 32 * 2304 + cb * 288;
#pragma unroll
        for (int i = 0; i < 9; ++i) {
            int idx = i * 256 + tid;               // 0..2303
            int o = idx / 72, f4 = idx % 72;
            float4 v = *(const float4*)&wbase[(size_t)o * 2304 + f4 * 4];
            slab[o * 289 + f4 * 4 + 0] = v.x;
            slab[o * 289 + f4 * 4 + 1] = v.y;
            slab[o * 289 + f4 * 4 + 2] = v.z;
            slab[o * 289 + f4 * 4 + 3] = v.w;
        }
        __syncthreads();
#pragma unroll
        for (int pass = 0; pass < 5; ++pass) {
            int rid = pass * 8 + (tid >> 5);
            if (rid < 36) {
                int kk = rid >> 2, q = rid & 3;
                int no = tid & 31;
                unsigned pk[4];
#pragma unroll
                for (int i = 0; i < 4; ++i) {
                    float f0 = slab[no * 289 + (q * 8 + 2 * i) * 9 + kk];
                    float f1 = slab[no * 289 + (q * 8 + 2 * i + 1) * 9 + kk];
                    pk[i] = pack_bf16(f0, f1);
                }
                size_t u = ((size_t)nt * 288 + kk * 32 + cb * 4 + q) * 32 + no;
                *(uint4*)&ws_b[u * 8] = make_uint4(pk[0], pk[1], pk[2], pk[3]);
            }
        }
    } else {
        int e = (bid - 64) * 256 + tid;       // 0..9215
        int lan = e & 31;                     // oc row
        int ku = e >> 5;                      // 0..287
        int kk = ku >> 5;
        int c0 = (ku & 31) * 8;
        int o = lan;
        float f[8];
#pragma unroll
        for (int j = 0; j < 8; ++j) {
            int c = c0 + j;
            float v = 0.f;
            if (o < 18)      v = off_w[((size_t)o * 256 + c) * 9 + kk];
            else if (o < 27) v = mask_w[((size_t)(o - 18) * 256 + c) * 9 + kk];
            f[j] = v;
        }
        unsigned pk[4];
#pragma unroll
        for (int i = 0; i < 4; ++i) pk[i] = pack_f16(f[2 * i], f[2 * i + 1]);
        *(uint4*)&ws_a2[(size_t)e * 8] = make_uint4(pk[0], pk[1], pk[2], pk[3]);
    }
}

// ---------------------------------------------------------------------------
// K2: offset/mask conv via f16 MFMA (round-2 verified structure).  Round-7
// change: build() issues all 32 loads into v[32] first, then packs/writes.
// ---------------------------------------------------------------------------
__global__ __launch_bounds__(512) void offmask_mfma_kernel(
    const float* __restrict__ x, const unsigned short* __restrict__ ws_a2,
    const float* __restrict__ off_b, const float* __restrict__ mask_b,
    float* __restrict__ ws_off)
{
    __shared__ uint4 bufB[2][2048];   // 64 KiB; aliased as red[] in epilogue
    const int bid = blockIdx.x;
    const int row = (bid & 7) * 32 + (bid >> 3);
    const int b = row >> 6, ho = row & 63;
    const int tid = threadIdx.x;
    const int l = tid & 63;
    const int w = tid >> 6;
    const int lan = l & 31, h = l >> 5;
    const float* xb = x + (size_t)b * 256 * 4096;

    floatx16 acc;
#pragma unroll
    for (int r = 0; r < 16; ++r) acc[r] = 0.f;

    const int n = l;                 // pixel within row
    const int ku0 = w;               // 0..7

    auto build = [&](int kk) {
        int ky = kk / 3, kx = kk - ky * 3;
        int hh = ho - 1 + ky;
        int px = n - 1 + kx;
        bool vh = (hh >= 0 && hh < 64);
        bool vx = (px >= 0 && px < 64);
        int base = hh * 64 + px;
        int buf = kk & 1;
        float v[32];
        // phase 1: issue ALL 32 independent loads (no packing between them)
#pragma unroll
        for (int j = 0; j < 4; ++j) {
            int c0 = (ku0 + 8 * j) * 8;
#pragma unroll
            for (int jj = 0; jj < 8; ++jj) {
                float t = 0.f;
                if (vh && vx) t = xb[(size_t)(c0 + jj) * 4096 + base];
                v[j * 8 + jj] = t;
            }
        }
        __builtin_amdgcn_sched_barrier(0);   // keep loads ahead of packs
        // phase 2: pack + LDS write
#pragma unroll
        for (int j = 0; j < 4; ++j) {
            unsigned pk[4];
#pragma unroll
            for (int i = 0; i < 4; ++i)
                pk[i] = pack_f16(v[j * 8 + 2 * i], v[j * 8 + 2 * i + 1]);
            bufB[buf][(ku0 + 8 * j) * 64 + n] = make_uint4(pk[0], pk[1], pk[2], pk[3]);
        }
    };

    const int ntile = w >> 2, kq = w & 3;
    auto domfma = [&](int kk) {
        int buf = kk & 1;
        const uint4* a4 = (const uint4*)ws_a2;
#pragma unroll
        for (int s4 = 0; s4 < 4; ++s4) {
            int s = kq * 4 + s4;         // K-step 0..15 within chunk
            int kul = s * 2 + h;         // local ku 0..31
            uint4 ua = a4[(size_t)(kk * 32 + kul) * 32 + lan];
            uint4 ub = bufB[buf][kul * 64 + ntile * 32 + lan];
            half8 a, bb;
            __builtin_memcpy(&a, &ua, 16);
            __builtin_memcpy(&bb, &ub, 16);
            acc = __builtin_amdgcn_mfma_f32_32x32x16_f16(a, bb, acc, 0, 0, 0);
        }
    };

    build(0);
    __syncthreads();
    for (int kk = 0; kk < 9; ++kk) {
        if (kk + 1 < 9) build(kk + 1);
        domfma(kk);
        __syncthreads();
    }

    // cross-wave partial-C reduction (4 K-quarters per n-tile)
    float* red = (float*)bufB;        // 8 waves x 64 lanes x 16 = 32 KiB
#pragma unroll
    for (int r = 0; r < 16; ++r) red[(w * 64 + l) * 16 + r] = acc[r];
    __syncthreads();
    for (int idx = tid; idx < 27 * 64; idx += 512) {
        int oc = idx >> 6, wo = idx & 63;
        int nt2 = wo >> 5, nn = wo & 31;
        int h2 = (oc >> 2) & 1;
        int r = (oc & 3) | ((oc >> 3) << 2);
        int lane2 = nn + 32 * h2;
        float s = 0.f;
#pragma unroll
        for (int kq2 = 0; kq2 < 4; ++kq2)
            s += red[((nt2 * 4 + kq2) * 64 + lane2) * 16 + r];
        float v;
        if (oc < 18) {
            v = s + off_b[oc];
        } else {
            float t = s + mask_b[oc - 18];
            v = 1.f / (1.f + expf(-t));
        }
        ws_off[(size_t)row * 1728 + idx] = v;
    }
}

// ---------------------------------------------------------------------------
// K3: fused deformable sampling + GEMM (verbatim round 5, bit-stable).
// ---------------------------------------------------------------------------
__global__ __launch_bounds__(1024) void deform_gemm_kernel(
    const float* __restrict__ x, const float* __restrict__ ws_off,
    const unsigned short* __restrict__ ws_b, const float* __restrict__ bias,
    float* __restrict__ out)
{
    __shared__ float offs[1728];
    __shared__ float biasl[256];
    __shared__ uint4 tile[2][2048];   // [buf][ku(32)*64 + n] : 8 bf16 each, 2x32KB

    const int bid = blockIdx.x;
    const int row = (bid & 7) * 32 + (bid >> 3);
    const int b = row >> 6, ho = row & 63;
    const int tid = threadIdx.x;
    const int l = tid & 63;
    const int wid = tid >> 6;          // 0..15
    const int lan = l & 31, h = l >> 5;

    for (int i = tid; i < 1728; i += 1024) offs[i] = ws_off[(size_t)row * 1728 + i];
    if (tid < 256) biasl[tid] = bias[tid];
    __syncthreads();

    const int p = wid;          // producer unit (valid when wid < 8)
    const int cw = wid - 8;     // consumer m-tile (valid when wid >= 8)
    const float* xb = x + (size_t)b * 256 * 4096;
    const uint4* wb4 = (const uint4*)ws_b;

    // producer per-tap state: premultiplied weight pairs + row base offsets
    float a00 = 0.f, a01 = 0.f, a10 = 0.f, a11 = 0.f;
    int e0 = 0, e1 = 0;

    floatx16 acc0, acc1;
#pragma unroll
    for (int r = 0; r < 16; ++r) { acc0[r] = 0.f; acc1[r] = 0.f; }

    auto compute_tap = [&](int kk) {
        int ky = kk / 3, kx = kk - ky * 3;
        float dy = offs[(2 * kk) * 64 + l];
        float dx = offs[(2 * kk + 1) * 64 + l];
        float mk = offs[(18 + kk) * 64 + l];
        float py = (float)(ho - 1 + ky) + dy;
        float px = (float)(l - 1 + kx) + dx;
        float y0f = floorf(py), x0f = floorf(px);
        float wy1 = py - y0f, wx1 = px - x0f;
        float wy0 = 1.f - wy1, wx0 = 1.f - wx1;
        int y0 = (int)y0f, xi0 = (int)x0f;
        int y1 = y0 + 1;
        float vy0 = (y0 >= 0 && y0 < 64) ? 1.f : 0.f;
        float vy1 = (y1 >= 0 && y1 < 64) ? 1.f : 0.f;
        float vx0 = (xi0 >= 0 && xi0 < 64) ? 1.f : 0.f;
        float vx1 = (xi0 >= -1 && xi0 < 63) ? 1.f : 0.f;   // validity of xi0+1
        // paired-load weights: v.x at col bx, v.y at col bx+1, bx = clamp(xi0,0,62)
        float wxa, wxb;
        if (xi0 < 0)        { wxa = wx1 * vx1; wxb = 0.f; }        // corner1 lands at v.x
        else if (xi0 >= 63) { wxa = 0.f;       wxb = wx0 * vx0; }  // corner0 lands at v.y
        else                { wxa = wx0;       wxb = wx1; }        // both valid
        float wr0 = wy0 * vy0 * mk, wr1 = wy1 * vy1 * mk;
        a00 = wr0 * wxa; a01 = wr0 * wxb;
        a10 = wr1 * wxa; a11 = wr1 * wxb;
        int yc0 = min(max(y0, 0), 63), yc1 = min(max(y1, 0), 63);
        int bx = min(max(xi0, 0), 62);
        e0 = yc0 * 64 + bx;
        e1 = yc1 * 64 + bx;
    };

    auto sample_tap = [&](int buf) {
        const float* bp = xb + (size_t)(p * 32) * 4096;
#pragma unroll
        for (int u = 0; u < 4; ++u) {
            unsigned pk[4];
#pragma unroll
            for (int j = 0; j < 4; ++j) {
                const float* q0 = bp + (size_t)(u * 8 + 2 * j) * 4096;
                const float* q1 = q0 + 4096;
                float2 r0a, r0b, r1a, r1b;
                __builtin_memcpy(&r0a, q0 + e0, 8);
                __builtin_memcpy(&r0b, q0 + e1, 8);
                __builtin_memcpy(&r1a, q1 + e0, 8);
                __builtin_memcpy(&r1b, q1 + e1, 8);
                float v0 = a00 * r0a.x + a01 * r0a.y + a10 * r0b.x + a11 * r0b.y;
                float v1 = a00 * r1a.x + a01 * r1a.y + a10 * r1b.x + a11 * r1b.y;
                pk[j] = pack_bf16(v0, v1);
            }
            tile[buf][(p * 4 + u) * 64 + l] = make_uint4(pk[0], pk[1], pk[2], pk[3]);
        }
    };

    auto do_mfma = [&](int kk, int buf) {
#pragma unroll
        for (int ks = 0; ks < 16; ++ks) {
            int kul = ks * 2 + h;          // local ku 0..31
            uint4 ua = wb4[((size_t)cw * 288 + kk * 32 + kul) * 32 + lan];
            uint4 ub0 = tile[buf][kul * 64 + lan];
            uint4 ub1 = tile[buf][kul * 64 + 32 + lan];
            short8 a, b0, b1;
            __builtin_memcpy(&a, &ua, 16);
            __builtin_memcpy(&b0, &ub0, 16);
            __builtin_memcpy(&b1, &ub1, 16);
            acc0 = __builtin_amdgcn_mfma_f32_32x32x16_bf16(a, b0, acc0, 0, 0, 0);
            acc1 = __builtin_amdgcn_mfma_f32_32x32x16_bf16(a, b1, acc1, 0, 0, 0);
        }
    };

    if (wid < 8) { compute_tap(0); sample_tap(0); }
    __syncthreads();

    for (int kk = 0; kk < 9; ++kk) {
        if (wid < 8) {
            if (kk + 1 < 9) {
                compute_tap(kk + 1);
                sample_tap((kk + 1) & 1);
            }
        } else {
            do_mfma(kk, kk & 1);
        }
        __syncthreads();
    }

    if (wid >= 8) {
#pragma unroll
        for (int nt = 0; nt < 2; ++nt) {
#pragma unroll
            for (int r = 0; r < 16; ++r) {
                int o = cw * 32 + (r & 3) + 8 * (r >> 2) + 4 * h;
                int woo = nt * 32 + lan;
                float v = (nt == 0) ? acc0[r] : acc1[r];
                out[(((size_t)b * 256 + o) * 64 + ho) * 64 + woo] = v + biasl[o];
            }
        }
    }
}

extern "C" void kernel_launch(void* const* d_in, const int* in_sizes, int n_in,
                              void* d_out, int out_size, void* d_ws, size_t ws_size,
                              hipStream_t stream) {
    const float* x      = (const float*)d_in[0];
    const float* weight = (const float*)d_in[1];
    const float* bias   = (const float*)d_in[2];
    const float* off_w  = (const float*)d_in[3];
    const float* off_b  = (const float*)d_in[4];
    const float* mask_w = (const float*)d_in[5];
    const float* mask_b = (const float*)d_in[6];
    float* out = (float*)d_out;

    float* ws_off = (float*)d_ws;                                      // 1,769,472 B
    unsigned short* ws_b  = (unsigned short*)((char*)d_ws + 1769472);  // 1,179,648 B
    unsigned short* ws_a2 = (unsigned short*)((char*)d_ws + 2949120);  //   147,456 B

    hipLaunchKernelGGL(weight_pack_kernel, dim3(100), dim3(256), 0, stream,
                       weight, off_w, mask_w, ws_b, ws_a2);
    hipLaunchKernelGGL(offmask_mfma_kernel, dim3(256), dim3(512), 0, stream,
                       x, ws_a2, off_b, mask_b, ws_off);
    hipLaunchKernelGGL(deform_gemm_kernel, dim3(256), dim3(1024), 0, stream,
                       x, ws_off, ws_b, bias, out);
}

// Round 8
// 235.236 us; speedup vs baseline: 1.0054x; 1.0054x over previous
//
#include <hip/hip_runtime.h>
#include <hip/hip_bf16.h>
#include <string.h>

// DeformableConv2d: B=4, C=256, O=256, H=W=64, K=3, pad=1, stride=1
// Round 8: K3 reshaped 1024->512 threads (8 waves: 4 producer x2 units,
// 4 consumer x2 m-tiles) to lift the 1024-thread 64-VGPR allocator cap
// (r5/r7 counters: VGPR=64, ~120MB spill traffic; r2's 512-thr K3 got 92).
// No __launch_bounds__ second arg (r6's route failed nondeterministically).
// Per-acc MFMA order identical to r5 -> absmax must stay 0.0078125.
// K1, K2 byte-identical to round 7.
// Workspace: ws_off 1769472 B | ws_b 1179648 B | ws_a2 147456 B = 3096576 B.

typedef __attribute__((ext_vector_type(8))) short short8;
typedef __attribute__((ext_vector_type(8))) _Float16 half8;
typedef __attribute__((ext_vector_type(16))) float floatx16;

__device__ __forceinline__ unsigned bfbits(float f) {
    unsigned u;
    __builtin_memcpy(&u, &f, 4);
    return (u + 0x7fffu + ((u >> 16) & 1u)) >> 16;   // RNE f32->bf16
}
__device__ __forceinline__ unsigned pack_bf16(float lo, float hi) {
    return bfbits(lo) | (bfbits(hi) << 16);
}
__device__ __forceinline__ unsigned pack_f16(float lo, float hi) {
    _Float16 a = (_Float16)lo, b = (_Float16)hi;
    unsigned short ua, ub;
    __builtin_memcpy(&ua, &a, 2);
    __builtin_memcpy(&ub, &b, 2);
    return (unsigned)ua | ((unsigned)ub << 16);
}

// ---------------------------------------------------------------------------
// K1: weight pack (verbatim round 4/5/7).
// ---------------------------------------------------------------------------
__global__ __launch_bounds__(256) void weight_pack_kernel(
    const float* __restrict__ w, const float* __restrict__ off_w,
    const float* __restrict__ mask_w,
    unsigned short* __restrict__ ws_b, unsigned short* __restrict__ ws_a2)
{
    __shared__ float slab[32 * 289];
    const int bid = blockIdx.x;
    const int tid = threadIdx.x;

    if (bid < 64) {
        const int nt = bid >> 3, cb = bid & 7;
        const float* wbase = w + (size_t)nt * 32 * 2304 + cb * 288;
#pragma unroll
        for (int i = 0; i < 9; ++i) {
            int idx = i * 256 + tid;               // 0..2303
            int o = idx / 72, f4 = idx % 72;
            float4 v = *(const float4*)&wbase[(size_t)o * 2304 + f4 * 4];
            slab[o * 289 + f4 * 4 + 0] = v.x;
            slab[o * 289 + f4 * 4 + 1] = v.y;
            slab[o * 289 + f4 * 4 + 2] = v.z;
            slab[o * 289 + f4 * 4 + 3] = v.w;
        }
        __syncthreads();
#pragma unroll
        for (int pass = 0; pass < 5; ++pass) {
            int rid = pass * 8 + (tid >> 5);
            if (rid < 36) {
                int kk = rid >> 2, q = rid & 3;
                int no = tid & 31;
                unsigned pk[4];
#pragma unroll
                for (int i = 0; i < 4; ++i) {
                    float f0 = slab[no * 289 + (q * 8 + 2 * i) * 9 + kk];
                    float f1 = slab[no * 289 + (q * 8 + 2 * i + 1) * 9 + kk];
                    pk[i] = pack_bf16(f0, f1);
                }
                size_t u = ((size_t)nt * 288 + kk * 32 + cb * 4 + q) * 32 + no;
                *(uint4*)&ws_b[u * 8] = make_uint4(pk[0], pk[1], pk[2], pk[3]);
            }
        }
    } else {
        int e = (bid - 64) * 256 + tid;       // 0..9215
        int lan = e & 31;                     // oc row
        int ku = e >> 5;                      // 0..287
        int kk = ku >> 5;
        int c0 = (ku & 31) * 8;
        int o = lan;
        float f[8];
#pragma unroll
        for (int j = 0; j < 8; ++j) {
            int c = c0 + j;
            float v = 0.f;
            if (o < 18)      v = off_w[((size_t)o * 256 + c) * 9 + kk];
            else if (o < 27) v = mask_w[((size_t)(o - 18) * 256 + c) * 9 + kk];
            f[j] = v;
        }
        unsigned pk[4];
#pragma unroll
        for (int i = 0; i < 4; ++i) pk[i] = pack_f16(f[2 * i], f[2 * i + 1]);
        *(uint4*)&ws_a2[(size_t)e * 8] = make_uint4(pk[0], pk[1], pk[2], pk[3]);
    }
}

// ---------------------------------------------------------------------------
// K2: offset/mask conv via f16 MFMA (verbatim round 7).
// ---------------------------------------------------------------------------
__global__ __launch_bounds__(512) void offmask_mfma_kernel(
    const float* __restrict__ x, const unsigned short* __restrict__ ws_a2,
    const float* __restrict__ off_b, const float* __restrict__ mask_b,
    float* __restrict__ ws_off)
{
    __shared__ uint4 bufB[2][2048];   // 64 KiB; aliased as red[] in epilogue
    const int bid = blockIdx.x;
    const int row = (bid & 7) * 32 + (bid >> 3);
    const int b = row >> 6, ho = row & 63;
    const int tid = threadIdx.x;
    const int l = tid & 63;
    const int w = tid >> 6;
    const int lan = l & 31, h = l >> 5;
    const float* xb = x + (size_t)b * 256 * 4096;

    floatx16 acc;
#pragma unroll
    for (int r = 0; r < 16; ++r) acc[r] = 0.f;

    const int n = l;                 // pixel within row
    const int ku0 = w;               // 0..7

    auto build = [&](int kk) {
        int ky = kk / 3, kx = kk - ky * 3;
        int hh = ho - 1 + ky;
        int px = n - 1 + kx;
        bool vh = (hh >= 0 && hh < 64);
        bool vx = (px >= 0 && px < 64);
        int base = hh * 64 + px;
        int buf = kk & 1;
        float v[32];
#pragma unroll
        for (int j = 0; j < 4; ++j) {
            int c0 = (ku0 + 8 * j) * 8;
#pragma unroll
            for (int jj = 0; jj < 8; ++jj) {
                float t = 0.f;
                if (vh && vx) t = xb[(size_t)(c0 + jj) * 4096 + base];
                v[j * 8 + jj] = t;
            }
        }
        __builtin_amdgcn_sched_barrier(0);   // keep loads ahead of packs
#pragma unroll
        for (int j = 0; j < 4; ++j) {
            unsigned pk[4];
#pragma unroll
            for (int i = 0; i < 4; ++i)
                pk[i] = pack_f16(v[j * 8 + 2 * i], v[j * 8 + 2 * i + 1]);
            bufB[buf][(ku0 + 8 * j) * 64 + n] = make_uint4(pk[0], pk[1], pk[2], pk[3]);
        }
    };

    const int ntile = w >> 2, kq = w & 3;
    auto domfma = [&](int kk) {
        int buf = kk & 1;
        const uint4* a4 = (const uint4*)ws_a2;
#pragma unroll
        for (int s4 = 0; s4 < 4; ++s4) {
            int s = kq * 4 + s4;         // K-step 0..15 within chunk
            int kul = s * 2 + h;         // local ku 0..31
            uint4 ua = a4[(size_t)(kk * 32 + kul) * 32 + lan];
            uint4 ub = bufB[buf][kul * 64 + ntile * 32 + lan];
            half8 a, bb;
            __builtin_memcpy(&a, &ua, 16);
            __builtin_memcpy(&bb, &ub, 16);
            acc = __builtin_amdgcn_mfma_f32_32x32x16_f16(a, bb, acc, 0, 0, 0);
        }
    };

    build(0);
    __syncthreads();
    for (int kk = 0; kk < 9; ++kk) {
        if (kk + 1 < 9) build(kk + 1);
        domfma(kk);
        __syncthreads();
    }

    // cross-wave partial-C reduction (4 K-quarters per n-tile)
    float* red = (float*)bufB;        // 8 waves x 64 lanes x 16 = 32 KiB
#pragma unroll
    for (int r = 0; r < 16; ++r) red[(w * 64 + l) * 16 + r] = acc[r];
    __syncthreads();
    for (int idx = tid; idx < 27 * 64; idx += 512) {
        int oc = idx >> 6, wo = idx & 63;
        int nt2 = wo >> 5, nn = wo & 31;
        int h2 = (oc >> 2) & 1;
        int r = (oc & 3) | ((oc >> 3) << 2);
        int lane2 = nn + 32 * h2;
        float s = 0.f;
#pragma unroll
        for (int kq2 = 0; kq2 < 4; ++kq2)
            s += red[((nt2 * 4 + kq2) * 64 + lane2) * 16 + r];
        float v;
        if (oc < 18) {
            v = s + off_b[oc];
        } else {
            float t = s + mask_b[oc - 18];
            v = 1.f / (1.f + expf(-t));
        }
        ws_off[(size_t)row * 1728 + idx] = v;
    }
}

// ---------------------------------------------------------------------------
// K3: fused deformable sampling + GEMM.  Round-5 verified math, reshaped to
// 512 threads / 8 waves: wid 0..3 producers (units 2*wid, 2*wid+1 = channels
// wid*64..wid*64+63 per tap), wid 4..7 consumers (m-tiles 2*(wid-4)+{0,1},
// 2 n-tiles each, B-frags reused across both m-tiles).
// ---------------------------------------------------------------------------
__global__ __launch_bounds__(512) void deform_gemm_kernel(
    const float* __restrict__ x, const float* __restrict__ ws_off,
    const unsigned short* __restrict__ ws_b, const float* __restrict__ bias,
    float* __restrict__ out)
{
    __shared__ float offs[1728];
    __shared__ float biasl[256];
    __shared__ uint4 tile[2][2048];   // [buf][ku(32)*64 + n] : 8 bf16 each, 2x32KB

    const int bid = blockIdx.x;
    const int row = (bid & 7) * 32 + (bid >> 3);
    const int b = row >> 6, ho = row & 63;
    const int tid = threadIdx.x;
    const int l = tid & 63;
    const int wid = tid >> 6;          // 0..7
    const int lan = l & 31, h = l >> 5;

    for (int i = tid; i < 1728; i += 512) offs[i] = ws_off[(size_t)row * 1728 + i];
    if (tid < 256) biasl[tid] = bias[tid];
    __syncthreads();

    const int cw0 = (wid - 4) * 2;     // consumer m-tile base (valid when wid >= 4)
    const float* xb = x + (size_t)b * 256 * 4096;
    const uint4* wb4 = (const uint4*)ws_b;

    // producer per-tap state: premultiplied weight pairs + row base offsets
    float a00 = 0.f, a01 = 0.f, a10 = 0.f, a11 = 0.f;
    int e0 = 0, e1 = 0;

    // consumer accumulators: [mi][nt]
    floatx16 acc00, acc01, acc10, acc11;
#pragma unroll
    for (int r = 0; r < 16; ++r) { acc00[r] = 0.f; acc01[r] = 0.f; acc10[r] = 0.f; acc11[r] = 0.f; }

    auto compute_tap = [&](int kk) {
        int ky = kk / 3, kx = kk - ky * 3;
        float dy = offs[(2 * kk) * 64 + l];
        float dx = offs[(2 * kk + 1) * 64 + l];
        float mk = offs[(18 + kk) * 64 + l];
        float py = (float)(ho - 1 + ky) + dy;
        float px = (float)(l - 1 + kx) + dx;
        float y0f = floorf(py), x0f = floorf(px);
        float wy1 = py - y0f, wx1 = px - x0f;
        float wy0 = 1.f - wy1, wx0 = 1.f - wx1;
        int y0 = (int)y0f, xi0 = (int)x0f;
        int y1 = y0 + 1;
        float vy0 = (y0 >= 0 && y0 < 64) ? 1.f : 0.f;
        float vy1 = (y1 >= 0 && y1 < 64) ? 1.f : 0.f;
        float vx0 = (xi0 >= 0 && xi0 < 64) ? 1.f : 0.f;
        float vx1 = (xi0 >= -1 && xi0 < 63) ? 1.f : 0.f;   // validity of xi0+1
        float wxa, wxb;
        if (xi0 < 0)        { wxa = wx1 * vx1; wxb = 0.f; }        // corner1 lands at v.x
        else if (xi0 >= 63) { wxa = 0.f;       wxb = wx0 * vx0; }  // corner0 lands at v.y
        else                { wxa = wx0;       wxb = wx1; }        // both valid
        float wr0 = wy0 * vy0 * mk, wr1 = wy1 * vy1 * mk;
        a00 = wr0 * wxa; a01 = wr0 * wxb;
        a10 = wr1 * wxa; a11 = wr1 * wxb;
        int yc0 = min(max(y0, 0), 63), yc1 = min(max(y1, 0), 63);
        int bx = min(max(xi0, 0), 62);
        e0 = yc0 * 64 + bx;
        e1 = yc1 * 64 + bx;
    };

    auto sample_unit = [&](int p, int buf) {
        const float* bp = xb + (size_t)(p * 32) * 4096;
#pragma unroll
        for (int u = 0; u < 4; ++u) {
            unsigned pk[4];
#pragma unroll
            for (int j = 0; j < 4; ++j) {
                const float* q0 = bp + (size_t)(u * 8 + 2 * j) * 4096;
                const float* q1 = q0 + 4096;
                float2 r0a, r0b, r1a, r1b;
                __builtin_memcpy(&r0a, q0 + e0, 8);
                __builtin_memcpy(&r0b, q0 + e1, 8);
                __builtin_memcpy(&r1a, q1 + e0, 8);
                __builtin_memcpy(&r1b, q1 + e1, 8);
                float v0 = a00 * r0a.x + a01 * r0a.y + a10 * r0b.x + a11 * r0b.y;
                float v1 = a00 * r1a.x + a01 * r1a.y + a10 * r1b.x + a11 * r1b.y;
                pk[j] = pack_bf16(v0, v1);
            }
            tile[buf][(p * 4 + u) * 64 + l] = make_uint4(pk[0], pk[1], pk[2], pk[3]);
        }
    };

    auto do_mfma = [&](int kk, int buf) {
#pragma unroll
        for (int ks = 0; ks < 16; ++ks) {
            int kul = ks * 2 + h;          // local ku 0..31
            uint4 ua0 = wb4[((size_t)cw0 * 288 + kk * 32 + kul) * 32 + lan];
            uint4 ua1 = wb4[((size_t)(cw0 + 1) * 288 + kk * 32 + kul) * 32 + lan];
            uint4 ub0 = tile[buf][kul * 64 + lan];
            uint4 ub1 = tile[buf][kul * 64 + 32 + lan];
            short8 a0, a1, b0, b1;
            __builtin_memcpy(&a0, &ua0, 16);
            __builtin_memcpy(&a1, &ua1, 16);
            __builtin_memcpy(&b0, &ub0, 16);
            __builtin_memcpy(&b1, &ub1, 16);
            acc00 = __builtin_amdgcn_mfma_f32_32x32x16_bf16(a0, b0, acc00, 0, 0, 0);
            acc01 = __builtin_amdgcn_mfma_f32_32x32x16_bf16(a0, b1, acc01, 0, 0, 0);
            acc10 = __builtin_amdgcn_mfma_f32_32x32x16_bf16(a1, b0, acc10, 0, 0, 0);
            acc11 = __builtin_amdgcn_mfma_f32_32x32x16_bf16(a1, b1, acc11, 0, 0, 0);
        }
    };

    if (wid < 4) {
        compute_tap(0);
        sample_unit(wid * 2, 0);
        sample_unit(wid * 2 + 1, 0);
    }
    __syncthreads();

    for (int kk = 0; kk < 9; ++kk) {
        if (wid < 4) {
            if (kk + 1 < 9) {
                compute_tap(kk + 1);
                sample_unit(wid * 2, (kk + 1) & 1);
                sample_unit(wid * 2 + 1, (kk + 1) & 1);
            }
        } else {
            do_mfma(kk, kk & 1);
        }
        __syncthreads();
    }

    if (wid >= 4) {
#pragma unroll
        for (int mi = 0; mi < 2; ++mi) {
            int cw = cw0 + mi;
#pragma unroll
            for (int nt = 0; nt < 2; ++nt) {
#pragma unroll
                for (int r = 0; r < 16; ++r) {
                    int o = cw * 32 + (r & 3) + 8 * (r >> 2) + 4 * h;
                    int woo = nt * 32 + lan;
                    float v;
                    if (mi == 0) v = (nt == 0) ? acc00[r] : acc01[r];
                    else         v = (nt == 0) ? acc10[r] : acc11[r];
                    out[(((size_t)b * 256 + o) * 64 + ho) * 64 + woo] = v + biasl[o];
                }
            }
        }
    }
}

extern "C" void kernel_launch(void* const* d_in, const int* in_sizes, int n_in,
                              void* d_out, int out_size, void* d_ws, size_t ws_size,
                              hipStream_t stream) {
    const float* x      = (const float*)d_in[0];
    const float* weight = (const float*)d_in[1];
    const float* bias   = (const float*)d_in[2];
    const float* off_w  = (const float*)d_in[3];
    const float* off_b  = (const float*)d_in[4];
    const float* mask_w = (const float*)d_in[5];
    const float* mask_b = (const float*)d_in[6];
    float* out = (float*)d_out;

    float* ws_off = (float*)d_ws;                                      // 1,769,472 B
    unsigned short* ws_b  = (unsigned short*)((char*)d_ws + 1769472);  // 1,179,648 B
    unsigned short* ws_a2 = (unsigned short*)((char*)d_ws + 2949120);  //   147,456 B

    hipLaunchKernelGGL(weight_pack_kernel, dim3(100), dim3(256), 0, stream,
                       weight, off_w, mask_w, ws_b, ws_a2);
    hipLaunchKernelGGL(offmask_mfma_kernel, dim3(256), dim3(512), 0, stream,
                       x, ws_a2, off_b, mask_b, ws_off);
    hipLaunchKernelGGL(deform_gemm_kernel, dim3(256), dim3(512), 0, stream,
                       x, ws_off, ws_b, bias, out);
}

// Round 9
// 199.372 us; speedup vs baseline: 1.1863x; 1.1799x over previous
//
#include <hip/hip_runtime.h>
#include <hip/hip_bf16.h>
#include <string.h>

// DeformableConv2d: B=4, C=256, O=256, H=W=64, K=3, pad=1, stride=1
// Round 9: K2 staging rewritten with global_load_lds async DMA.
//   Theory: K2's hidden ~100us = per-load latency serialization of its
//   (perfectly coalesced) staging loads. Async DMA -> LDS removes the
//   VGPR round-trip entirely; one barrier drain per row; x row staged
//   once per ky (not once per tap). B-tile values bit-identical.
// K1, K3 byte-identical to round 8 (absmax canary 0.0078125 must hold).
// Workspace: ws_off 1769472 B | ws_b 1179648 B | ws_a2 147456 B = 3096576 B.

typedef __attribute__((ext_vector_type(8))) short short8;
typedef __attribute__((ext_vector_type(8))) _Float16 half8;
typedef __attribute__((ext_vector_type(16))) float floatx16;

__device__ __forceinline__ unsigned bfbits(float f) {
    unsigned u;
    __builtin_memcpy(&u, &f, 4);
    return (u + 0x7fffu + ((u >> 16) & 1u)) >> 16;   // RNE f32->bf16
}
__device__ __forceinline__ unsigned pack_bf16(float lo, float hi) {
    return bfbits(lo) | (bfbits(hi) << 16);
}
__device__ __forceinline__ unsigned pack_f16(float lo, float hi) {
    _Float16 a = (_Float16)lo, b = (_Float16)hi;
    unsigned short ua, ub;
    __builtin_memcpy(&ua, &a, 2);
    __builtin_memcpy(&ub, &b, 2);
    return (unsigned)ua | ((unsigned)ub << 16);
}

// async global->LDS DMA, 4 B per lane; lane l's data lands at lds + l*4
__device__ __forceinline__ void gl_lds4(const float* g, float* l) {
    __builtin_amdgcn_global_load_lds(
        (const __attribute__((address_space(1))) unsigned int*)g,
        (__attribute__((address_space(3))) unsigned int*)l,
        4, 0, 0);
}

// ---------------------------------------------------------------------------
// K1: weight pack (verbatim round 4/5/7/8).
// ---------------------------------------------------------------------------
__global__ __launch_bounds__(256) void weight_pack_kernel(
    const float* __restrict__ w, const float* __restrict__ off_w,
    const float* __restrict__ mask_w,
    unsigned short* __restrict__ ws_b, unsigned short* __restrict__ ws_a2)
{
    __shared__ float slab[32 * 289];
    const int bid = blockIdx.x;
    const int tid = threadIdx.x;

    if (bid < 64) {
        const int nt = bid >> 3, cb = bid & 7;
        const float* wbase = w + (size_t)nt * 32 * 2304 + cb * 288;
#pragma unroll
        for (int i = 0; i < 9; ++i) {
            int idx = i * 256 + tid;               // 0..2303
            int o = idx / 72, f4 = idx % 72;
            float4 v = *(const float4*)&wbase[(size_t)o * 2304 + f4 * 4];
            slab[o * 289 + f4 * 4 + 0] = v.x;
            slab[o * 289 + f4 * 4 + 1] = v.y;
            slab[o * 289 + f4 * 4 + 2] = v.z;
            slab[o * 289 + f4 * 4 + 3] = v.w;
        }
        __syncthreads();
#pragma unroll
        for (int pass = 0; pass < 5; ++pass) {
            int rid = pass * 8 + (tid >> 5);
            if (rid < 36) {
                int kk = rid >> 2, q = rid & 3;
                int no = tid & 31;
                unsigned pk[4];
#pragma unroll
                for (int i = 0; i < 4; ++i) {
                    float f0 = slab[no * 289 + (q * 8 + 2 * i) * 9 + kk];
                    float f1 = slab[no * 289 + (q * 8 + 2 * i + 1) * 9 + kk];
                    pk[i] = pack_bf16(f0, f1);
                }
                size_t u = ((size_t)nt * 288 + kk * 32 + cb * 4 + q) * 32 + no;
                *(uint4*)&ws_b[u * 8] = make_uint4(pk[0], pk[1], pk[2], pk[3]);
            }
        }
    } else {
        int e = (bid - 64) * 256 + tid;       // 0..9215
        int lan = e & 31;                     // oc row
        int ku = e >> 5;                      // 0..287
        int kk = ku >> 5;
        int c0 = (ku & 31) * 8;
        int o = lan;
        float f[8];
#pragma unroll
        for (int j = 0; j < 8; ++j) {
            int c = c0 + j;
            float v = 0.f;
            if (o < 18)      v = off_w[((size_t)o * 256 + c) * 9 + kk];
            else if (o < 27) v = mask_w[((size_t)(o - 18) * 256 + c) * 9 + kk];
            f[j] = v;
        }
        unsigned pk[4];
#pragma unroll
        for (int i = 0; i < 4; ++i) pk[i] = pack_f16(f[2 * i], f[2 * i + 1]);
        *(uint4*)&ws_a2[(size_t)e * 8] = make_uint4(pk[0], pk[1], pk[2], pk[3]);
    }
}

// ---------------------------------------------------------------------------
// K2: offset/mask conv via f16 MFMA.  Round-9 structure:
//   per ky: async-DMA x row (256 ch x 64 cols f32) -> LDS stage (64 KiB),
//   barrier (drains DMA), then per kx: build B-tile from LDS (bit-identical
//   values to rounds 2-8), barrier, MFMA.  domfma/reduction verbatim.
// ---------------------------------------------------------------------------
__global__ __launch_bounds__(512) void offmask_mfma_kernel(
    const float* __restrict__ x, const unsigned short* __restrict__ ws_a2,
    const float* __restrict__ off_b, const float* __restrict__ mask_b,
    float* __restrict__ ws_off)
{
    __shared__ float stage[256 * 64];     // 64 KiB: x[.][hh][.] for one row
    __shared__ uint4 bufB[2][2048];       // 64 KiB; aliased as red[] in epilogue
    const int bid = blockIdx.x;
    const int row = (bid & 7) * 32 + (bid >> 3);
    const int b = row >> 6, ho = row & 63;
    const int tid = threadIdx.x;
    const int l = tid & 63;
    const int w = tid >> 6;
    const int lan = l & 31, h = l >> 5;
    const float* xb = x + (size_t)b * 256 * 4096;

    floatx16 acc;
#pragma unroll
    for (int r = 0; r < 16; ++r) acc[r] = 0.f;

    const int n = l;                 // pixel within row
    const int ku0 = w;               // 0..7
    const int ntile = w >> 2, kq = w & 3;

    auto stage_row = [&](int hh) {
        if (hh >= 0 && hh < 64) {
            const float* src = xb + hh * 64;
#pragma unroll
            for (int i = 0; i < 32; ++i) {
                int c = w * 32 + i;                 // wave-uniform channel
                gl_lds4(src + (size_t)c * 4096 + l, &stage[c * 64]);
            }
        } else {
#pragma unroll
            for (int i = 0; i < 32; ++i) {
                int c = w * 32 + i;
                stage[c * 64 + l] = 0.f;
            }
        }
    };

    auto build = [&](int kk, int kx) {
        int px = n - 1 + kx;
        bool vx = (px >= 0 && px < 64);
        int pxc = vx ? px : 0;
        int buf = kk & 1;
#pragma unroll
        for (int j = 0; j < 4; ++j) {
            int ku = ku0 + 8 * j;
            int c0 = ku * 8;
            float v[8];
#pragma unroll
            for (int jj = 0; jj < 8; ++jj) {
                float t = stage[(c0 + jj) * 64 + pxc];
                v[jj] = vx ? t : 0.f;
            }
            unsigned pk[4];
#pragma unroll
            for (int i = 0; i < 4; ++i) pk[i] = pack_f16(v[2 * i], v[2 * i + 1]);
            bufB[buf][ku * 64 + n] = make_uint4(pk[0], pk[1], pk[2], pk[3]);
        }
    };

    auto domfma = [&](int kk) {
        int buf = kk & 1;
        const uint4* a4 = (const uint4*)ws_a2;
#pragma unroll
        for (int s4 = 0; s4 < 4; ++s4) {
            int s = kq * 4 + s4;         // K-step 0..15 within chunk
            int kul = s * 2 + h;         // local ku 0..31
            uint4 ua = a4[(size_t)(kk * 32 + kul) * 32 + lan];
            uint4 ub = bufB[buf][kul * 64 + ntile * 32 + lan];
            half8 a, bb;
            __builtin_memcpy(&a, &ua, 16);
            __builtin_memcpy(&bb, &ub, 16);
            acc = __builtin_amdgcn_mfma_f32_32x32x16_f16(a, bb, acc, 0, 0, 0);
        }
    };

    for (int ky = 0; ky < 3; ++ky) {
        __syncthreads();                 // prior builds done reading stage
        stage_row(ho - 1 + ky);
        __syncthreads();                 // DMA drained (vmcnt(0) before barrier)
#pragma unroll
        for (int kx = 0; kx < 3; ++kx) {
            int kk = ky * 3 + kx;
            build(kk, kx);
            __syncthreads();
            domfma(kk);
        }
    }
    __syncthreads();                     // last domfma done before red alias

    // cross-wave partial-C reduction (4 K-quarters per n-tile) - verbatim
    float* red = (float*)bufB;           // 8 waves x 64 lanes x 16 = 32 KiB
#pragma unroll
    for (int r = 0; r < 16; ++r) red[(w * 64 + l) * 16 + r] = acc[r];
    __syncthreads();
    for (int idx = tid; idx < 27 * 64; idx += 512) {
        int oc = idx >> 6, wo = idx & 63;
        int nt2 = wo >> 5, nn = wo & 31;
        int h2 = (oc >> 2) & 1;
        int r = (oc & 3) | ((oc >> 3) << 2);
        int lane2 = nn + 32 * h2;
        float s = 0.f;
#pragma unroll
        for (int kq2 = 0; kq2 < 4; ++kq2)
            s += red[((nt2 * 4 + kq2) * 64 + lane2) * 16 + r];
        float v;
        if (oc < 18) {
            v = s + off_b[oc];
        } else {
            float t = s + mask_b[oc - 18];
            v = 1.f / (1.f + expf(-t));
        }
        ws_off[(size_t)row * 1728 + idx] = v;
    }
}

// ---------------------------------------------------------------------------
// K3: fused deformable sampling + GEMM (verbatim round 8, 512 threads).
// ---------------------------------------------------------------------------
__global__ __launch_bounds__(512) void deform_gemm_kernel(
    const float* __restrict__ x, const float* __restrict__ ws_off,
    const unsigned short* __restrict__ ws_b, const float* __restrict__ bias,
    float* __restrict__ out)
{
    __shared__ float offs[1728];
    __shared__ float biasl[256];
    __shared__ uint4 tile[2][2048];   // [buf][ku(32)*64 + n] : 8 bf16 each, 2x32KB

    const int bid = blockIdx.x;
    const int row = (bid & 7) * 32 + (bid >> 3);
    const int b = row >> 6, ho = row & 63;
    const int tid = threadIdx.x;
    const int l = tid & 63;
    const int wid = tid >> 6;          // 0..7
    const int lan = l & 31, h = l >> 5;

    for (int i = tid; i < 1728; i += 512) offs[i] = ws_off[(size_t)row * 1728 + i];
    if (tid < 256) biasl[tid] = bias[tid];
    __syncthreads();

    const int cw0 = (wid - 4) * 2;     // consumer m-tile base (valid when wid >= 4)
    const float* xb = x + (size_t)b * 256 * 4096;
    const uint4* wb4 = (const uint4*)ws_b;

    float a00 = 0.f, a01 = 0.f, a10 = 0.f, a11 = 0.f;
    int e0 = 0, e1 = 0;

    floatx16 acc00, acc01, acc10, acc11;
#pragma unroll
    for (int r = 0; r < 16; ++r) { acc00[r] = 0.f; acc01[r] = 0.f; acc10[r] = 0.f; acc11[r] = 0.f; }

    auto compute_tap = [&](int kk) {
        int ky = kk / 3, kx = kk - ky * 3;
        float dy = offs[(2 * kk) * 64 + l];
        float dx = offs[(2 * kk + 1) * 64 + l];
        float mk = offs[(18 + kk) * 64 + l];
        float py = (float)(ho - 1 + ky) + dy;
        float px = (float)(l - 1 + kx) + dx;
        float y0f = floorf(py), x0f = floorf(px);
        float wy1 = py - y0f, wx1 = px - x0f;
        float wy0 = 1.f - wy1, wx0 = 1.f - wx1;
        int y0 = (int)y0f, xi0 = (int)x0f;
        int y1 = y0 + 1;
        float vy0 = (y0 >= 0 && y0 < 64) ? 1.f : 0.f;
        float vy1 = (y1 >= 0 && y1 < 64) ? 1.f : 0.f;
        float vx0 = (xi0 >= 0 && xi0 < 64) ? 1.f : 0.f;
        float vx1 = (xi0 >= -1 && xi0 < 63) ? 1.f : 0.f;   // validity of xi0+1
        float wxa, wxb;
        if (xi0 < 0)        { wxa = wx1 * vx1; wxb = 0.f; }        // corner1 lands at v.x
        else if (xi0 >= 63) { wxa = 0.f;       wxb = wx0 * vx0; }  // corner0 lands at v.y
        else                { wxa = wx0;       wxb = wx1; }        // both valid
        float wr0 = wy0 * vy0 * mk, wr1 = wy1 * vy1 * mk;
        a00 = wr0 * wxa; a01 = wr0 * wxb;
        a10 = wr1 * wxa; a11 = wr1 * wxb;
        int yc0 = min(max(y0, 0), 63), yc1 = min(max(y1, 0), 63);
        int bx = min(max(xi0, 0), 62);
        e0 = yc0 * 64 + bx;
        e1 = yc1 * 64 + bx;
    };

    auto sample_unit = [&](int p, int buf) {
        const float* bp = xb + (size_t)(p * 32) * 4096;
#pragma unroll
        for (int u = 0; u < 4; ++u) {
            unsigned pk[4];
#pragma unroll
            for (int j = 0; j < 4; ++j) {
                const float* q0 = bp + (size_t)(u * 8 + 2 * j) * 4096;
                const float* q1 = q0 + 4096;
                float2 r0a, r0b, r1a, r1b;
                __builtin_memcpy(&r0a, q0 + e0, 8);
                __builtin_memcpy(&r0b, q0 + e1, 8);
                __builtin_memcpy(&r1a, q1 + e0, 8);
                __builtin_memcpy(&r1b, q1 + e1, 8);
                float v0 = a00 * r0a.x + a01 * r0a.y + a10 * r0b.x + a11 * r0b.y;
                float v1 = a00 * r1a.x + a01 * r1a.y + a10 * r1b.x + a11 * r1b.y;
                pk[j] = pack_bf16(v0, v1);
            }
            tile[buf][(p * 4 + u) * 64 + l] = make_uint4(pk[0], pk[1], pk[2], pk[3]);
        }
    };

    auto do_mfma = [&](int kk, int buf) {
#pragma unroll
        for (int ks = 0; ks < 16; ++ks) {
            int kul = ks * 2 + h;          // local ku 0..31
            uint4 ua0 = wb4[((size_t)cw0 * 288 + kk * 32 + kul) * 32 + lan];
            uint4 ua1 = wb4[((size_t)(cw0 + 1) * 288 + kk * 32 + kul) * 32 + lan];
            uint4 ub0 = tile[buf][kul * 64 + lan];
            uint4 ub1 = tile[buf][kul * 64 + 32 + lan];
            short8 a0, a1, b0, b1;
            __builtin_memcpy(&a0, &ua0, 16);
            __builtin_memcpy(&a1, &ua1, 16);
            __builtin_memcpy(&b0, &ub0, 16);
            __builtin_memcpy(&b1, &ub1, 16);
            acc00 = __builtin_amdgcn_mfma_f32_32x32x16_bf16(a0, b0, acc00, 0, 0, 0);
            acc01 = __builtin_amdgcn_mfma_f32_32x32x16_bf16(a0, b1, acc01, 0, 0, 0);
            acc10 = __builtin_amdgcn_mfma_f32_32x32x16_bf16(a1, b0, acc10, 0, 0, 0);
            acc11 = __builtin_amdgcn_mfma_f32_32x32x16_bf16(a1, b1, acc11, 0, 0, 0);
        }
    };

    if (wid < 4) {
        compute_tap(0);
        sample_unit(wid * 2, 0);
        sample_unit(wid * 2 + 1, 0);
    }
    __syncthreads();

    for (int kk = 0; kk < 9; ++kk) {
        if (wid < 4) {
            if (kk + 1 < 9) {
                compute_tap(kk + 1);
                sample_unit(wid * 2, (kk + 1) & 1);
                sample_unit(wid * 2 + 1, (kk + 1) & 1);
            }
        } else {
            do_mfma(kk, kk & 1);
        }
        __syncthreads();
    }

    if (wid >= 4) {
#pragma unroll
        for (int mi = 0; mi < 2; ++mi) {
            int cw = cw0 + mi;
#pragma unroll
            for (int nt = 0; nt < 2; ++nt) {
#pragma unroll
                for (int r = 0; r < 16; ++r) {
                    int o = cw * 32 + (r & 3) + 8 * (r >> 2) + 4 * h;
                    int woo = nt * 32 + lan;
                    float v;
                    if (mi == 0) v = (nt == 0) ? acc00[r] : acc01[r];
                    else         v = (nt == 0) ? acc10[r] : acc11[r];
                    out[(((size_t)b * 256 + o) * 64 + ho) * 64 + woo] = v + biasl[o];
                }
            }
        }
    }
}

extern "C" void kernel_launch(void* const* d_in, const int* in_sizes, int n_in,
                              void* d_out, int out_size, void* d_ws, size_t ws_size,
                              hipStream_t stream) {
    const float* x      = (const float*)d_in[0];
    const float* weight = (const float*)d_in[1];
    const float* bias   = (const float*)d_in[2];
    const float* off_w  = (const float*)d_in[3];
    const float* off_b  = (const float*)d_in[4];
    const float* mask_w = (const float*)d_in[5];
    const float* mask_b = (const float*)d_in[6];
    float* out = (float*)d_out;

    float* ws_off = (float*)d_ws;                                      // 1,769,472 B
    unsigned short* ws_b  = (unsigned short*)((char*)d_ws + 1769472);  // 1,179,648 B
    unsigned short* ws_a2 = (unsigned short*)((char*)d_ws + 2949120);  //   147,456 B

    hipLaunchKernelGGL(weight_pack_kernel, dim3(100), dim3(256), 0, stream,
                       weight, off_w, mask_w, ws_b, ws_a2);
    hipLaunchKernelGGL(offmask_mfma_kernel, dim3(256), dim3(512), 0, stream,
                       x, ws_a2, off_b, mask_b, ws_off);
    hipLaunchKernelGGL(deform_gemm_kernel, dim3(256), dim3(512), 0, stream,
                       x, ws_off, ws_b, bias, out);
}

// Round 10
// 184.044 us; speedup vs baseline: 1.2851x; 1.0833x over previous
//
#include <hip/hip_runtime.h>
#include <hip/hip_bf16.h>
#include <string.h>

// DeformableConv2d: B=4, C=256, O=256, H=W=64, K=3, pad=1, stride=1
// Round 10: K3 merged producer/consumer roles (one change vs r9).
//   All 8 waves sample unit wid (32 ch, 64 paired loads/tap) AND own m-tile
//   wid (32 acc VGPRs). Per iter: sample(kk+1)->tile[(kk+1)&1]; mfma(kk) on
//   tile[kk&1]; barrier. 2 waves/SIMD overlap gather latency with MFMA;
//   in-flight load state halved to fit the register budget.
//   Per-acc K-order identical to r8 -> absmax must stay 0.0078125.
// K1, K2 byte-identical to round 9.
// Workspace: ws_off 1769472 B | ws_b 1179648 B | ws_a2 147456 B = 3096576 B.

typedef __attribute__((ext_vector_type(8))) short short8;
typedef __attribute__((ext_vector_type(8))) _Float16 half8;
typedef __attribute__((ext_vector_type(16))) float floatx16;

__device__ __forceinline__ unsigned bfbits(float f) {
    unsigned u;
    __builtin_memcpy(&u, &f, 4);
    return (u + 0x7fffu + ((u >> 16) & 1u)) >> 16;   // RNE f32->bf16
}
__device__ __forceinline__ unsigned pack_bf16(float lo, float hi) {
    return bfbits(lo) | (bfbits(hi) << 16);
}
__device__ __forceinline__ unsigned pack_f16(float lo, float hi) {
    _Float16 a = (_Float16)lo, b = (_Float16)hi;
    unsigned short ua, ub;
    __builtin_memcpy(&ua, &a, 2);
    __builtin_memcpy(&ub, &b, 2);
    return (unsigned)ua | ((unsigned)ub << 16);
}

// async global->LDS DMA, 4 B per lane; lane l's data lands at lds + l*4
__device__ __forceinline__ void gl_lds4(const float* g, float* l) {
    __builtin_amdgcn_global_load_lds(
        (const __attribute__((address_space(1))) unsigned int*)g,
        (__attribute__((address_space(3))) unsigned int*)l,
        4, 0, 0);
}

// ---------------------------------------------------------------------------
// K1: weight pack (verbatim rounds 4-9).
// ---------------------------------------------------------------------------
__global__ __launch_bounds__(256) void weight_pack_kernel(
    const float* __restrict__ w, const float* __restrict__ off_w,
    const float* __restrict__ mask_w,
    unsigned short* __restrict__ ws_b, unsigned short* __restrict__ ws_a2)
{
    __shared__ float slab[32 * 289];
    const int bid = blockIdx.x;
    const int tid = threadIdx.x;

    if (bid < 64) {
        const int nt = bid >> 3, cb = bid & 7;
        const float* wbase = w + (size_t)nt * 32 * 2304 + cb * 288;
#pragma unroll
        for (int i = 0; i < 9; ++i) {
            int idx = i * 256 + tid;               // 0..2303
            int o = idx / 72, f4 = idx % 72;
            float4 v = *(const float4*)&wbase[(size_t)o * 2304 + f4 * 4];
            slab[o * 289 + f4 * 4 + 0] = v.x;
            slab[o * 289 + f4 * 4 + 1] = v.y;
            slab[o * 289 + f4 * 4 + 2] = v.z;
            slab[o * 289 + f4 * 4 + 3] = v.w;
        }
        __syncthreads();
#pragma unroll
        for (int pass = 0; pass < 5; ++pass) {
            int rid = pass * 8 + (tid >> 5);
            if (rid < 36) {
                int kk = rid >> 2, q = rid & 3;
                int no = tid & 31;
                unsigned pk[4];
#pragma unroll
                for (int i = 0; i < 4; ++i) {
                    float f0 = slab[no * 289 + (q * 8 + 2 * i) * 9 + kk];
                    float f1 = slab[no * 289 + (q * 8 + 2 * i + 1) * 9 + kk];
                    pk[i] = pack_bf16(f0, f1);
                }
                size_t u = ((size_t)nt * 288 + kk * 32 + cb * 4 + q) * 32 + no;
                *(uint4*)&ws_b[u * 8] = make_uint4(pk[0], pk[1], pk[2], pk[3]);
            }
        }
    } else {
        int e = (bid - 64) * 256 + tid;       // 0..9215
        int lan = e & 31;                     // oc row
        int ku = e >> 5;                      // 0..287
        int kk = ku >> 5;
        int c0 = (ku & 31) * 8;
        int o = lan;
        float f[8];
#pragma unroll
        for (int j = 0; j < 8; ++j) {
            int c = c0 + j;
            float v = 0.f;
            if (o < 18)      v = off_w[((size_t)o * 256 + c) * 9 + kk];
            else if (o < 27) v = mask_w[((size_t)(o - 18) * 256 + c) * 9 + kk];
            f[j] = v;
        }
        unsigned pk[4];
#pragma unroll
        for (int i = 0; i < 4; ++i) pk[i] = pack_f16(f[2 * i], f[2 * i + 1]);
        *(uint4*)&ws_a2[(size_t)e * 8] = make_uint4(pk[0], pk[1], pk[2], pk[3]);
    }
}

// ---------------------------------------------------------------------------
// K2: offset/mask conv via f16 MFMA with global_load_lds staging
// (verbatim round 9).
// ---------------------------------------------------------------------------
__global__ __launch_bounds__(512) void offmask_mfma_kernel(
    const float* __restrict__ x, const unsigned short* __restrict__ ws_a2,
    const float* __restrict__ off_b, const float* __restrict__ mask_b,
    float* __restrict__ ws_off)
{
    __shared__ float stage[256 * 64];     // 64 KiB: x[.][hh][.] for one row
    __shared__ uint4 bufB[2][2048];       // 64 KiB; aliased as red[] in epilogue
    const int bid = blockIdx.x;
    const int row = (bid & 7) * 32 + (bid >> 3);
    const int b = row >> 6, ho = row & 63;
    const int tid = threadIdx.x;
    const int l = tid & 63;
    const int w = tid >> 6;
    const int lan = l & 31, h = l >> 5;
    const float* xb = x + (size_t)b * 256 * 4096;

    floatx16 acc;
#pragma unroll
    for (int r = 0; r < 16; ++r) acc[r] = 0.f;

    const int n = l;                 // pixel within row
    const int ku0 = w;               // 0..7
    const int ntile = w >> 2, kq = w & 3;

    auto stage_row = [&](int hh) {
        if (hh >= 0 && hh < 64) {
            const float* src = xb + hh * 64;
#pragma unroll
            for (int i = 0; i < 32; ++i) {
                int c = w * 32 + i;                 // wave-uniform channel
                gl_lds4(src + (size_t)c * 4096 + l, &stage[c * 64]);
            }
        } else {
#pragma unroll
            for (int i = 0; i < 32; ++i) {
                int c = w * 32 + i;
                stage[c * 64 + l] = 0.f;
            }
        }
    };

    auto build = [&](int kk, int kx) {
        int px = n - 1 + kx;
        bool vx = (px >= 0 && px < 64);
        int pxc = vx ? px : 0;
        int buf = kk & 1;
#pragma unroll
        for (int j = 0; j < 4; ++j) {
            int ku = ku0 + 8 * j;
            int c0 = ku * 8;
            float v[8];
#pragma unroll
            for (int jj = 0; jj < 8; ++jj) {
                float t = stage[(c0 + jj) * 64 + pxc];
                v[jj] = vx ? t : 0.f;
            }
            unsigned pk[4];
#pragma unroll
            for (int i = 0; i < 4; ++i) pk[i] = pack_f16(v[2 * i], v[2 * i + 1]);
            bufB[buf][ku * 64 + n] = make_uint4(pk[0], pk[1], pk[2], pk[3]);
        }
    };

    auto domfma = [&](int kk) {
        int buf = kk & 1;
        const uint4* a4 = (const uint4*)ws_a2;
#pragma unroll
        for (int s4 = 0; s4 < 4; ++s4) {
            int s = kq * 4 + s4;         // K-step 0..15 within chunk
            int kul = s * 2 + h;         // local ku 0..31
            uint4 ua = a4[(size_t)(kk * 32 + kul) * 32 + lan];
            uint4 ub = bufB[buf][kul * 64 + ntile * 32 + lan];
            half8 a, bb;
            __builtin_memcpy(&a, &ua, 16);
            __builtin_memcpy(&bb, &ub, 16);
            acc = __builtin_amdgcn_mfma_f32_32x32x16_f16(a, bb, acc, 0, 0, 0);
        }
    };

    for (int ky = 0; ky < 3; ++ky) {
        __syncthreads();                 // prior builds done reading stage
        stage_row(ho - 1 + ky);
        __syncthreads();                 // DMA drained (vmcnt(0) before barrier)
#pragma unroll
        for (int kx = 0; kx < 3; ++kx) {
            int kk = ky * 3 + kx;
            build(kk, kx);
            __syncthreads();
            domfma(kk);
        }
    }
    __syncthreads();                     // last domfma done before red alias

    // cross-wave partial-C reduction (4 K-quarters per n-tile) - verbatim
    float* red = (float*)bufB;           // 8 waves x 64 lanes x 16 = 32 KiB
#pragma unroll
    for (int r = 0; r < 16; ++r) red[(w * 64 + l) * 16 + r] = acc[r];
    __syncthreads();
    for (int idx = tid; idx < 27 * 64; idx += 512) {
        int oc = idx >> 6, wo = idx & 63;
        int nt2 = wo >> 5, nn = wo & 31;
        int h2 = (oc >> 2) & 1;
        int r = (oc & 3) | ((oc >> 3) << 2);
        int lane2 = nn + 32 * h2;
        float s = 0.f;
#pragma unroll
        for (int kq2 = 0; kq2 < 4; ++kq2)
            s += red[((nt2 * 4 + kq2) * 64 + lane2) * 16 + r];
        float v;
        if (oc < 18) {
            v = s + off_b[oc];
        } else {
            float t = s + mask_b[oc - 18];
            v = 1.f / (1.f + expf(-t));
        }
        ws_off[(size_t)row * 1728 + idx] = v;
    }
}

// ---------------------------------------------------------------------------
// K3: fused deformable sampling + GEMM, merged roles.  512 threads / 8 waves;
// wave wid samples unit wid (channels wid*32..wid*32+31) and owns m-tile wid
// (o = wid*32..wid*32+31, 2 n-tiles).  One barrier per tap interval.
// compute_tap / sample_unit / MFMA K-order identical to round 8 (verified).
// ---------------------------------------------------------------------------
__global__ __launch_bounds__(512) void deform_gemm_kernel(
    const float* __restrict__ x, const float* __restrict__ ws_off,
    const unsigned short* __restrict__ ws_b, const float* __restrict__ bias,
    float* __restrict__ out)
{
    __shared__ float offs[1728];
    __shared__ float biasl[256];
    __shared__ uint4 tile[2][2048];   // [buf][ku(32)*64 + n] : 8 bf16 each, 2x32KB

    const int bid = blockIdx.x;
    const int row = (bid & 7) * 32 + (bid >> 3);
    const int b = row >> 6, ho = row & 63;
    const int tid = threadIdx.x;
    const int l = tid & 63;
    const int wid = tid >> 6;          // 0..7
    const int lan = l & 31, h = l >> 5;

    for (int i = tid; i < 1728; i += 512) offs[i] = ws_off[(size_t)row * 1728 + i];
    if (tid < 256) biasl[tid] = bias[tid];
    __syncthreads();

    const float* xb = x + (size_t)b * 256 * 4096;
    const uint4* wb4 = (const uint4*)ws_b;

    // producer per-tap state: premultiplied weight pairs + row base offsets
    float a00 = 0.f, a01 = 0.f, a10 = 0.f, a11 = 0.f;
    int e0 = 0, e1 = 0;

    // consumer accumulators: m-tile wid x 2 n-tiles
    floatx16 acc0, acc1;
#pragma unroll
    for (int r = 0; r < 16; ++r) { acc0[r] = 0.f; acc1[r] = 0.f; }

    auto compute_tap = [&](int kk) {
        int ky = kk / 3, kx = kk - ky * 3;
        float dy = offs[(2 * kk) * 64 + l];
        float dx = offs[(2 * kk + 1) * 64 + l];
        float mk = offs[(18 + kk) * 64 + l];
        float py = (float)(ho - 1 + ky) + dy;
        float px = (float)(l - 1 + kx) + dx;
        float y0f = floorf(py), x0f = floorf(px);
        float wy1 = py - y0f, wx1 = px - x0f;
        float wy0 = 1.f - wy1, wx0 = 1.f - wx1;
        int y0 = (int)y0f, xi0 = (int)x0f;
        int y1 = y0 + 1;
        float vy0 = (y0 >= 0 && y0 < 64) ? 1.f : 0.f;
        float vy1 = (y1 >= 0 && y1 < 64) ? 1.f : 0.f;
        float vx0 = (xi0 >= 0 && xi0 < 64) ? 1.f : 0.f;
        float vx1 = (xi0 >= -1 && xi0 < 63) ? 1.f : 0.f;   // validity of xi0+1
        float wxa, wxb;
        if (xi0 < 0)        { wxa = wx1 * vx1; wxb = 0.f; }        // corner1 lands at v.x
        else if (xi0 >= 63) { wxa = 0.f;       wxb = wx0 * vx0; }  // corner0 lands at v.y
        else                { wxa = wx0;       wxb = wx1; }        // both valid
        float wr0 = wy0 * vy0 * mk, wr1 = wy1 * vy1 * mk;
        a00 = wr0 * wxa; a01 = wr0 * wxb;
        a10 = wr1 * wxa; a11 = wr1 * wxb;
        int yc0 = min(max(y0, 0), 63), yc1 = min(max(y1, 0), 63);
        int bx = min(max(xi0, 0), 62);
        e0 = yc0 * 64 + bx;
        e1 = yc1 * 64 + bx;
    };

    auto sample_unit = [&](int p, int buf) {
        const float* bp = xb + (size_t)(p * 32) * 4096;
#pragma unroll
        for (int u = 0; u < 4; ++u) {
            unsigned pk[4];
#pragma unroll
            for (int j = 0; j < 4; ++j) {
                const float* q0 = bp + (size_t)(u * 8 + 2 * j) * 4096;
                const float* q1 = q0 + 4096;
                float2 r0a, r0b, r1a, r1b;
                __builtin_memcpy(&r0a, q0 + e0, 8);
                __builtin_memcpy(&r0b, q0 + e1, 8);
                __builtin_memcpy(&r1a, q1 + e0, 8);
                __builtin_memcpy(&r1b, q1 + e1, 8);
                float v0 = a00 * r0a.x + a01 * r0a.y + a10 * r0b.x + a11 * r0b.y;
                float v1 = a00 * r1a.x + a01 * r1a.y + a10 * r1b.x + a11 * r1b.y;
                pk[j] = pack_bf16(v0, v1);
            }
            tile[buf][(p * 4 + u) * 64 + l] = make_uint4(pk[0], pk[1], pk[2], pk[3]);
        }
    };

    auto do_mfma = [&](int kk, int buf) {
#pragma unroll
        for (int ks = 0; ks < 16; ++ks) {
            int kul = ks * 2 + h;          // local ku 0..31
            uint4 ua = wb4[((size_t)wid * 288 + kk * 32 + kul) * 32 + lan];
            uint4 ub0 = tile[buf][kul * 64 + lan];
            uint4 ub1 = tile[buf][kul * 64 + 32 + lan];
            short8 a, b0, b1;
            __builtin_memcpy(&a, &ua, 16);
            __builtin_memcpy(&b0, &ub0, 16);
            __builtin_memcpy(&b1, &ub1, 16);
            acc0 = __builtin_amdgcn_mfma_f32_32x32x16_bf16(a, b0, acc0, 0, 0, 0);
            acc1 = __builtin_amdgcn_mfma_f32_32x32x16_bf16(a, b1, acc1, 0, 0, 0);
        }
    };

    compute_tap(0);
    sample_unit(wid, 0);
    __syncthreads();

    for (int kk = 0; kk < 9; ++kk) {
        if (kk + 1 < 9) {
            compute_tap(kk + 1);
            sample_unit(wid, (kk + 1) & 1);
        }
        do_mfma(kk, kk & 1);
        __syncthreads();
    }

    // epilogue: wave wid owns m-tile wid
#pragma unroll
    for (int nt = 0; nt < 2; ++nt) {
#pragma unroll
        for (int r = 0; r < 16; ++r) {
            int o = wid * 32 + (r & 3) + 8 * (r >> 2) + 4 * h;
            int woo = nt * 32 + lan;
            float v = (nt == 0) ? acc0[r] : acc1[r];
            out[(((size_t)b * 256 + o) * 64 + ho) * 64 + woo] = v + biasl[o];
        }
    }
}

extern "C" void kernel_launch(void* const* d_in, const int* in_sizes, int n_in,
                              void* d_out, int out_size, void* d_ws, size_t ws_size,
                              hipStream_t stream) {
    const float* x      = (const float*)d_in[0];
    const float* weight = (const float*)d_in[1];
    const float* bias   = (const float*)d_in[2];
    const float* off_w  = (const float*)d_in[3];
    const float* off_b  = (const float*)d_in[4];
    const float* mask_w = (const float*)d_in[5];
    const float* mask_b = (const float*)d_in[6];
    float* out = (float*)d_out;

    float* ws_off = (float*)d_ws;                                      // 1,769,472 B
    unsigned short* ws_b  = (unsigned short*)((char*)d_ws + 1769472);  // 1,179,648 B
    unsigned short* ws_a2 = (unsigned short*)((char*)d_ws + 2949120);  //   147,456 B

    hipLaunchKernelGGL(weight_pack_kernel, dim3(100), dim3(256), 0, stream,
                       weight, off_w, mask_w, ws_b, ws_a2);
    hipLaunchKernelGGL(offmask_mfma_kernel, dim3(256), dim3(512), 0, stream,
                       x, ws_a2, off_b, mask_b, ws_off);
    hipLaunchKernelGGL(deform_gemm_kernel, dim3(256), dim3(512), 0, stream,
                       x, ws_off, ws_b, bias, out);
}